// Round 3
// baseline (949.291 us; speedup 1.0000x reference)
//
#include <hip/hip_runtime.h>

#define Mc 512
#define Nc 1024
#define WRc 16
#define Bc 4096

// Compressed c2v row state, indexed by step-slot s = t mod 512 (cn_order is a
// fixed per-sweep permutation). A min-sum row's c2v is fully determined by:
//   m1c, m2c : clipped min / second-min of |v2c| over the row (uint bits)
//   meta     : signs16 | argmin<<16 | total_parity<<20
// Reconstruction: c2v_j = (j==a1 ? m2c : m1c) with sign (parity ^ sign_j).
// Bit-exact incl. ties (non-unique min => m2==m1 => uniform m1 everywhere).
// 12 B per (slot, batch) -> 24 MB total; each wave only touches its own 4
// batch slices -> wave-private -> L2-resident (~3 MB/XCD).
// Sweep 0 never reads it, so no init needed (idempotent across launches).
__device__ uint2 g_mm[(size_t)Mc * Bc];
__device__ unsigned g_meta[(size_t)Mc * Bc];

#define DPPI(old, src, ctrl) \
  __builtin_amdgcn_update_dpp((old), (src), (ctrl), 0xF, 0xF, false)

static __device__ __forceinline__ int imin(int a, int b) { return a < b ? a : b; }
static __device__ __forceinline__ int imax(int a, int b) { return a > b ? a : b; }

#define CLIPB 0x41A00000  /* bits of 20.0f */

__global__ __launch_bounds__(64) void ldpc_kernel(
    const float* __restrict__ llr, const int* __restrict__ H,
    const int* __restrict__ iters_p, const int* __restrict__ cn_order,
    float* __restrict__ out) {
  const int tid = threadIdx.x;
  const int g = tid >> 4;    // batch sub-slot within wave (0..3) == DPP row
  const int j = tid & 15;    // edge position within check node
  const int b0 = blockIdx.x * 4;
  const int b = b0 + g;

  __shared__ float vn[4][Nc];                 // 16 KB
  __shared__ unsigned short hp[Mc * WRc];     // 16 KB: H rows in cn_order order

  for (int i = tid; i < 4 * Nc; i += 64)
    vn[i >> 10][i & (Nc - 1)] = llr[(size_t)(b0 + (i >> 10)) * Nc + (i & (Nc - 1))];
  for (int i = tid; i < Mc * WRc; i += 64)
    hp[i] = (unsigned short)H[cn_order[i >> 4] * WRc + (i & 15)];
  __syncthreads();

  const int T = iters_p[0] * Mc;              // multiple of 4 (iters*512)

  const int INFB = 0x7F800000;

  // ---- pipeline prime ----
  int idx_cur = hp[j];
  int idx_nxt = hp[(1 & (Mc - 1)) * WRc + j];
  int idx_f2  = hp[(2 & (Mc - 1)) * WRc + j];
  float v = vn[g][idx_cur];                    // gather for t=0
  float c2vf[4] = {0.0f, 0.0f, 0.0f, 0.0f};    // t=0..3 are sweep 0

  for (int tb = 0; tb < T; tb += 4) {
#pragma unroll
    for (int k = 0; k < 4; ++k) {
      const int t = tb + k;

      // ================= serial chain =================
      const float v2c = v - c2vf[k];
      const int ab = __float_as_int(v2c) & 0x7FFFFFFF;

      // inclusive prefix/suffix int-min scans (nonneg floats order as ints)
      int p = ab;
      p = imin(p, DPPI(INFB, p, 0x111));
      p = imin(p, DPPI(INFB, p, 0x112));
      p = imin(p, DPPI(INFB, p, 0x114));
      p = imin(p, DPPI(INFB, p, 0x118));
      int s = ab;
      s = imin(s, DPPI(INFB, s, 0x101));
      s = imin(s, DPPI(INFB, s, 0x102));
      s = imin(s, DPPI(INFB, s, 0x104));
      s = imin(s, DPPI(INFB, s, 0x108));
      const int pe = DPPI(INFB, p, 0x111);   // exclusive
      const int se = DPPI(INFB, s, 0x101);
      const int loo = imin(pe, se);          // leave-one-out min, exact
      const int ampi = imin(loo, CLIPB);     // clip (int min valid: nonneg)

      // sign parity via ballot (parallel to the min chain)
      const unsigned long long sbal = __ballot(v2c < 0.0f);
      const unsigned sgn16 = ((unsigned)(sbal >> (g * 16))) & 0xFFFFu;
      const unsigned tp = (unsigned)__popc(sgn16) & 1u;
      const unsigned sb = (sgn16 >> j) & 1u;
      const unsigned ncb = (unsigned)ampi | ((tp ^ sb) << 31);
      const float nc = __uint_as_float(ncb);

      vn[g][idx_cur] = v2c + nc;   // scatter (step t)
      v = vn[g][idx_nxt];          // gather (step t+1) — back-to-back, in-order DS
      // ================================================

      // ---- off-chain: compress row state + store (12 B) ----
      const int m1 = imin(loo, ab);                       // global min (uniform)
      const unsigned long long mbal = __ballot(ab == m1);
      const unsigned mg = ((unsigned)(mbal >> (g * 16))) & 0xFFFFu;
      const int a1 = __ffs(mg) - 1;                       // first argmin
      int mx = loo;                                       // m2 = max_j loo_j
      mx = imax(mx, DPPI(0, mx, 0x121));
      mx = imax(mx, DPPI(0, mx, 0x122));
      mx = imax(mx, DPPI(0, mx, 0x124));
      mx = imax(mx, DPPI(0, mx, 0x128));
      const unsigned m1c = (unsigned)imin(m1, CLIPB);
      const unsigned m2c = (unsigned)imin(mx, CLIPB);
      const unsigned meta = sgn16 | ((unsigned)a1 << 16) | (tp << 20);
      const int wsl = (t & (Mc - 1)) * Bc + b;
      if (j == 0) {
        g_mm[wsl] = make_uint2(m1c, m2c);
        g_meta[wsl] = meta;
      }

      // ---- off-chain: depth-4 prefetch + reconstruct for step t+4 ----
      const int t4 = t + 4;
      const int rsl = (t4 & (Mc - 1)) * Bc + b;           // written 508 steps ago
      const uint2 mm = g_mm[rsl];                          // 16-lane broadcast load
      const unsigned met = g_meta[rsl];
      const unsigned psb = (met >> j) & 1u;
      const unsigned ptp = (met >> 20) & 1u;
      const int pa1 = (int)((met >> 16) & 15u);
      const unsigned pai = (j == pa1) ? mm.y : mm.x;
      const float rec = __uint_as_float(pai | ((ptp ^ psb) << 31));
      c2vf[k] = (t4 >= Mc) ? rec : 0.0f;                   // sweep 0 -> 0

      idx_cur = idx_nxt;                                   // rotate idx pipeline
      idx_nxt = idx_f2;
      idx_f2 = hp[((t + 3) & (Mc - 1)) * WRc + j];         // idx prefetch, depth 3
    }
  }

  // Hard decision. Single-wave block: wave-synchronous, no barrier needed.
  for (int i = tid; i < 4 * Nc; i += 64) {
    const int gg = i >> 10, n = i & (Nc - 1);
    out[(size_t)(b0 + gg) * Nc + n] = (vn[gg][n] < 0.0f) ? 1.0f : 0.0f;
  }
}

extern "C" void kernel_launch(void* const* d_in, const int* in_sizes, int n_in,
                              void* d_out, int out_size, void* d_ws, size_t ws_size,
                              hipStream_t stream) {
  const float* llr = (const float*)d_in[0];
  const int* H = (const int*)d_in[1];
  const int* iters_p = (const int*)d_in[2];
  const int* cn_order = (const int*)d_in[3];
  float* out = (float*)d_out;
  ldpc_kernel<<<dim3(Bc / 4), dim3(64), 0, stream>>>(llr, H, iters_p, cn_order, out);
}

// Round 6
// 679.894 us; speedup vs baseline: 1.3962x; 1.3962x over previous
//
#include <hip/hip_runtime.h>

#define Mc 512
#define Nc 1024
#define WRc 16
#define Bc 4096

// Layered min-sum; 16 lanes = one check-node row, 4 batch elems / wave.
// Compressed row state (m1c, m2c, signs16|argmin|parity) lives in an LDS
// circular FIFO indexed by slot s = t mod 512 (cn_order is a fixed per-sweep
// permutation): write slot t, read slot (t+4) mod 512 == written 508 steps
// ago. Bit-exact reconstruction: c2v_j = (j==a1 ? m2c : m1c) signed by
// (parity ^ sign_j); ties collapse correctly (m2c==m1c).
// LDS = 16K vn + 3*8K state = 40960 B -> exactly 4 blocks/CU.

#define DPPI(old, src, ctrl) \
  __builtin_amdgcn_update_dpp((old), (src), (ctrl), 0xF, 0xF, false)

static __device__ __forceinline__ int imin(int a, int b) { return a < b ? a : b; }
static __device__ __forceinline__ int imax(int a, int b) { return a > b ? a : b; }

#define CLIPB 0x41A00000  /* bits of 20.0f */
#define INFB  0x7F800000

__global__ __launch_bounds__(64) void ldpc_kernel(
    const float* __restrict__ llr, const int* __restrict__ H,
    const int* __restrict__ iters_p, const int* __restrict__ cn_order,
    float* __restrict__ out) {
  const int tid = threadIdx.x;
  const int g = tid >> 4;    // batch sub-slot (0..3) == DPP row
  const int j = tid & 15;    // edge position in the check node
  const int b0 = blockIdx.x * 4;

  __shared__ float vn[4][Nc];          // 16 KB
  __shared__ unsigned stA[Mc * 4];     // 8 KB: m1c  per (slot, g)
  __shared__ unsigned stB[Mc * 4];     // 8 KB: m2c
  __shared__ unsigned stC[Mc * 4];     // 8 KB: signs16 | a1<<16 | parity<<20

  for (int i = tid; i < 4 * Nc; i += 64)
    vn[i >> 10][i & (Nc - 1)] = llr[(size_t)(b0 + (i >> 10)) * Nc + (i & (Nc - 1))];
  __syncthreads();

  const int T = iters_p[0] * Mc;   // iters*512, multiple of 4
  const int shft = g * 16;

  // ---- prime the metadata pipelines (read-only, L1/L2-hot, off-chain) ----
  int cn5 = cn_order[5 & (Mc - 1)];
  int cn6 = cn_order[6 & (Mc - 1)];
  int cn7 = cn_order[7 & (Mc - 1)];
  int cn8 = cn_order[8 & (Mc - 1)];
  int i0 = H[cn_order[0] * WRc + j];            // idx slot 0 (scatter t=0)
  int i1 = H[cn_order[1 & (Mc - 1)] * WRc + j]; // idx slots 1..4
  int i2 = H[cn_order[2 & (Mc - 1)] * WRc + j];
  int i3 = H[cn_order[3 & (Mc - 1)] * WRc + j];
  int i4 = H[cn_order[4 & (Mc - 1)] * WRc + j];
  float v = vn[g][i0];                          // gather for t=0
  float c2vf[4] = {0.0f, 0.0f, 0.0f, 0.0f};     // t=0..3 are sweep 0

  for (int tb = 0; tb < T; tb += 4) {
#pragma unroll
    for (int k = 0; k < 4; ++k) {
      const int t = tb + k;

      // ================= serial chain =================
      const float v2c = v - c2vf[k];
      const int ab = __float_as_int(v2c) & 0x7FFFFFFF;

      int p = ab;                         // inclusive prefix-min (row_shr)
      p = imin(p, DPPI(INFB, p, 0x111));
      p = imin(p, DPPI(INFB, p, 0x112));
      p = imin(p, DPPI(INFB, p, 0x114));
      p = imin(p, DPPI(INFB, p, 0x118));
      int s = ab;                         // inclusive suffix-min (row_shl)
      s = imin(s, DPPI(INFB, s, 0x101));
      s = imin(s, DPPI(INFB, s, 0x102));
      s = imin(s, DPPI(INFB, s, 0x104));
      s = imin(s, DPPI(INFB, s, 0x108));
      const int pe = DPPI(INFB, p, 0x111);   // exclusive
      const int se = DPPI(INFB, s, 0x101);
      const int loo = imin(pe, se);          // leave-one-out min (exact)
      const int ampi = imin(loo, CLIPB);     // clip

      const unsigned long long sbal = __ballot(v2c < 0.0f);
      const unsigned sgn16 = ((unsigned)(sbal >> shft)) & 0xFFFFu;
      const unsigned tp = (unsigned)__popc(sgn16) & 1u;
      const unsigned sb = ((unsigned)__float_as_int(v2c)) >> 31;
      const float nc = __uint_as_float((unsigned)ampi | ((tp ^ sb) << 31));

      vn[g][i0] = v2c + nc;    // scatter (slot t)
      v = vn[g][i1];           // gather (slot t+1) — back-to-back, in-order DS
      // ================================================

      // ---- off-chain: compress + store row state (12 B/group, LDS) ----
      const int m1 = imin(loo, ab);                        // row min (uniform)
      const unsigned long long mbal = __ballot(ab == m1);
      const int a1 = __ffs((unsigned)((mbal >> shft) & 0xFFFFu)) - 1;
      int mx = loo;                                        // m2 = max_j loo_j
      mx = imax(mx, DPPI(0, mx, 0x121));
      mx = imax(mx, DPPI(0, mx, 0x122));
      mx = imax(mx, DPPI(0, mx, 0x124));
      mx = imax(mx, DPPI(0, mx, 0x128));
      const int wsl = (t & (Mc - 1)) * 4 + g;
      if (j == 0) {
        stA[wsl] = (unsigned)imin(m1, CLIPB);
        stB[wsl] = (unsigned)imin(mx, CLIPB);
        stC[wsl] = sgn16 | ((unsigned)a1 << 16) | (tp << 20);
      }

      // ---- off-chain: depth-4 state read + reconstruct for step t+4 ----
      const int t4 = t + 4;
      const int rsl = (t4 & (Mc - 1)) * 4 + g;   // written 508 steps ago
      const unsigned m1c = stA[rsl];             // broadcast reads, no conflict
      const unsigned m2c = stB[rsl];
      const unsigned met = stC[rsl];
      const unsigned psb = (met >> j) & 1u;
      const unsigned ptp = (met >> 20) & 1u;
      const unsigned pai = (j == (int)((met >> 16) & 15u)) ? m2c : m1c;
      const float rec = __uint_as_float(pai | ((ptp ^ psb) << 31));
      c2vf[k] = (t4 >= Mc) ? rec : 0.0f;         // sweep 0 -> 0 (garbage masked)

      // ---- off-chain: rotate metadata queues (depth-4 cover each) ----
      i0 = i1; i1 = i2; i2 = i3; i3 = i4;
      i4 = H[cn5 * WRc + j];                     // idx for slot t+5
      cn5 = cn6; cn6 = cn7; cn7 = cn8;
      cn8 = cn_order[(t + 9) & (Mc - 1)];        // cn for slot t+9
    }
  }

  // Hard decision. Single-wave block: wave-synchronous, no barrier needed.
  for (int i = tid; i < 4 * Nc; i += 64) {
    const int gg = i >> 10, n = i & (Nc - 1);
    out[(size_t)(b0 + gg) * Nc + n] = (vn[gg][n] < 0.0f) ? 1.0f : 0.0f;
  }
}

extern "C" void kernel_launch(void* const* d_in, const int* in_sizes, int n_in,
                              void* d_out, int out_size, void* d_ws, size_t ws_size,
                              hipStream_t stream) {
  const float* llr = (const float*)d_in[0];
  const int* H = (const int*)d_in[1];
  const int* iters_p = (const int*)d_in[2];
  const int* cn_order = (const int*)d_in[3];
  float* out = (float*)d_out;
  ldpc_kernel<<<dim3(Bc / 4), dim3(64), 0, stream>>>(llr, H, iters_p, cn_order, out);
}